// Round 11
// baseline (76.234 us; speedup 1.0000x reference)
//
#include <hip/hip_runtime.h>

// SphericalEmbedding round 11: single-launch fusion. The serialized
// wt_convert pre-kernel (~4-6us of the 55.45) is replaced by per-block
// W-band conversion into LDS (41.5KB L2-resident reads, overlaps with other
// blocks' store phases). No workspace, one kernel.
//   per block: convert W band -> Wl[128][104] bf16 (LDS) || harmonics ->
//   H[128][104] bf16 (LDS); MFMA D[ch,pt]; half-tile x2 LDS C-staging
//   epilogue (R8-proven) -> linear f32x4 stores.

typedef __attribute__((ext_vector_type(8))) short bf16x8;
typedef __attribute__((ext_vector_type(4))) float f32x4;

#define BM 128
#define BN 128
#define LDA 104          // H/Wl row stride (bf16): 208 B -> 2-way aliasing (free)
#define KPAD 96
#define LDCC 132         // C chunk row stride (dwords)

// ---- compile-time normalization table ----------------------------------
constexpr double PI_D = 3.14159265358979323846;
constexpr double csqrt_c(double v) {
  if (v <= 0.0) return 0.0;
  double g = v < 1.0 ? 1.0 : v;
  for (int i = 0; i < 100; ++i) g = 0.5 * (g + v / g);
  return g;
}
struct Norms { float c[81]; };
constexpr Norms make_norms() {
  Norms n{};
  for (int l = 0; l <= 8; ++l)
    for (int m = -l; m <= l; ++m) {
      int am = m < 0 ? -m : m;
      double fr = 1.0;
      for (int i = l - am + 1; i <= l + am; ++i) fr *= (double)i;
      double v = csqrt_c((2.0 * l + 1.0) / (4.0 * PI_D) / fr);
      if (m < 0 && (am & 1)) v = -v;
      n.c[l * l + l + m] = (float)v;
    }
  return n;
}
constexpr Norms NORMS = make_norms();

__device__ __forceinline__ unsigned f2bf(float f) {   // RTN-even f32 -> bf16 bits
  unsigned u = __float_as_uint(f);
  return (u + 0x7fffu + ((u >> 16) & 1u)) >> 16;
}

// ---- fused kernel -------------------------------------------------------
__global__ __launch_bounds__(256)
void sph_mfma_kernel(const float* __restrict__ pos,
                     const float* __restrict__ W,
                     float* __restrict__ out, int nch)
{
  // Layout: [H 26624 B][Wl 26624 B] concurrently; C (33792 B) unions from 0
  // after both are dead.
  __shared__ __align__(16) char smem[2 * BM * LDA * 2];    // 53248 B
  unsigned short* H  = reinterpret_cast<unsigned short*>(smem);
  unsigned short* Wl = reinterpret_cast<unsigned short*>(smem + BM * LDA * 2);
  float*          C  = reinterpret_cast<float*>(smem);

  const int tid  = threadIdx.x;
  const int lane = tid & 63;
  const int wid  = tid >> 6;                       // 4 waves: 2(ch) x 2(pt)
  const int wc   = wid >> 1, wp = wid & 1;
  const int l15  = lane & 15, l4 = lane >> 4;
  const int mblk = blockIdx.y, nblk = blockIdx.x;

  // ---- phase 0: convert this block's W band -> Wl bf16 ------------------
  // W [81][nch] f32; band ch in [nblk*BN, nblk*BN+128). Transposed store.
  {
    const float* wband = W + (size_t)nblk * BN;
    for (int idx = tid; idx < 81 * (BN / 4); idx += 256) {
      const int k  = idx / (BN / 4);               // 0..80
      const int c4 = idx - k * (BN / 4);           // 0..31
      const float4 w = *reinterpret_cast<const float4*>(
          wband + (size_t)k * nch + c4 * 4);
      unsigned short* col = &Wl[(c4 * 4) * LDA + k];
      col[0 * LDA] = (unsigned short)f2bf(w.x);
      col[1 * LDA] = (unsigned short)f2bf(w.y);
      col[2 * LDA] = (unsigned short)f2bf(w.z);
      col[3 * LDA] = (unsigned short)f2bf(w.w);
    }
    if (tid < BM) {                                // K padding rows 81..95
#pragma unroll
      for (int i = 81; i < KPAD; ++i) Wl[tid * LDA + i] = 0;
    }
  }

  // ---- phase 1: streaming harmonics -> H bf16 (R10-proven) --------------
  if (tid < BM) {
    const int gp = mblk * BM + tid;
    const float px = pos[gp * 3 + 0];
    const float py = pos[gp * 3 + 1];
    const float pz = pos[gp * 3 + 2];
    const float r   = sqrtf(px * px + py * py + pz * pz);
    const float inv = 1.0f / (r + 1e-8f);
    const float xn = px * inv, yn = py * inv, zn = pz * inv;
    const float x = fminf(1.0f, fmaxf(-1.0f, zn));     // cos(theta)
    const float s = sqrtf(fmaxf(0.0f, 1.0f - x * x));  // sin(theta)
    const float rho = sqrtf(xn * xn + yn * yn);
    const float c1  = rho > 0.0f ? xn / rho : 1.0f;    // cos(phi)

    float cm[9];
    cm[0] = 1.0f; cm[1] = c1;
#pragma unroll
    for (int m = 2; m <= 8; ++m) cm[m] = 2.0f * c1 * cm[m - 1] - cm[m - 2];

    unsigned short* hrow = &H[tid * LDA];
    float Pmm_prev = 1.0f;
#pragma unroll
    for (int m = 0; m <= 8; ++m) {
      const float Pmm = (m == 0) ? 1.0f : -(float)(2 * m - 1) * s * Pmm_prev;
      Pmm_prev = Pmm;
      {
        const float base = Pmm * cm[m];                  // l = m
        hrow[m * m + 2 * m] = (unsigned short)f2bf(NORMS.c[m * m + 2 * m] * base);
        if (m > 0)
          hrow[m * m] = (unsigned short)f2bf(NORMS.c[m * m] * base);
      }
      float Pl2 = Pmm, Pl1 = 0.0f;
      if (m + 1 <= 8) {
        Pl1 = (float)(2 * m + 1) * x * Pmm;              // l = m+1
        const int l = m + 1;
        const float base = Pl1 * cm[m];
        hrow[l * l + l + m] = (unsigned short)f2bf(NORMS.c[l * l + l + m] * base);
        if (m > 0)
          hrow[l * l + l - m] = (unsigned short)f2bf(NORMS.c[l * l + l - m] * base);
      }
#pragma unroll
      for (int l = m + 2; l <= 8; ++l) {
        const float Pl = ((float)(2 * l - 1) * x * Pl1
                          - (float)(l + m - 1) * Pl2) * (1.0f / (float)(l - m));
        Pl2 = Pl1; Pl1 = Pl;
        const float base = Pl * cm[m];
        hrow[l * l + l + m] = (unsigned short)f2bf(NORMS.c[l * l + l + m] * base);
        if (m > 0)
          hrow[l * l + l - m] = (unsigned short)f2bf(NORMS.c[l * l + l - m] * base);
      }
    }
#pragma unroll
    for (int i = 81; i < KPAD; ++i) hrow[i] = 0;
  }

  __syncthreads();

  // ---- MFMA: D[ch, pt], per-kk fragment loads (both from LDS) -----------
  f32x4 acc[4][4] = {};
#pragma unroll
  for (int kk = 0; kk < 3; ++kk) {
    bf16x8 wfrag[4], hfrag[4];
#pragma unroll
    for (int i = 0; i < 4; ++i)
      wfrag[i] = *reinterpret_cast<const bf16x8*>(
          &Wl[(wc * 64 + i * 16 + l15) * LDA + kk * 32 + l4 * 8]);
#pragma unroll
    for (int i = 0; i < 4; ++i)
      hfrag[i] = *reinterpret_cast<const bf16x8*>(
          &H[(wp * 64 + i * 16 + l15) * LDA + kk * 32 + l4 * 8]);
#pragma unroll
    for (int cmr = 0; cmr < 4; ++cmr)
#pragma unroll
      for (int pn = 0; pn < 4; ++pn)
        acc[cmr][pn] = __builtin_amdgcn_mfma_f32_16x16x32_bf16(
            wfrag[cmr], hfrag[pn], acc[cmr][pn], 0, 0, 0);
  }

  __syncthreads();   // H and Wl dead; smem becomes the C half-tile

  // ---- epilogue: two half-tile passes through LDS (R8-proven) ------------
  // D row(ch) = wc*64 + cmr*16 + l4*4 + reg; D col(pt) = wp*64 + pn*16 + l15
  const size_t obase = (size_t)(mblk * BM) * nch + (size_t)nblk * BN;
#pragma unroll
  for (int h = 0; h < 2; ++h) {
#pragma unroll
    for (int q = 0; q < 2; ++q) {
      const int lr = wp * 32 + q * 16 + l15;        // local chunk row (point)
#pragma unroll
      for (int cmr = 0; cmr < 4; ++cmr)
        *reinterpret_cast<f32x4*>(&C[lr * LDCC + wc * 64 + cmr * 16 + l4 * 4]) =
            acc[cmr][2 * h + q];
    }
    __syncthreads();
#pragma unroll
    for (int it = 0; it < 8; ++it) {
      const int f  = it * 1024 + tid * 4;           // flat float idx in chunk
      const int lr = f >> 7;                        // chunk row 0..63
      const int cc = f & 127;                       // channel col
      const int gr = (lr >> 5) * 64 + h * 32 + (lr & 31);   // block point row
      const f32x4 v = *reinterpret_cast<const f32x4*>(&C[lr * LDCC + cc]);
      *reinterpret_cast<f32x4*>(out + obase + (size_t)gr * nch + cc) = v;
    }
    if (h == 0) __syncthreads();
  }
}

extern "C" void kernel_launch(void* const* d_in, const int* in_sizes, int n_in,
                              void* d_out, int out_size, void* d_ws, size_t ws_size,
                              hipStream_t stream) {
  const float* pos = (const float*)d_in[0];   // [npts, 3]
  const float* W   = (const float*)d_in[1];   // [81, nch]
  float*       out = (float*)d_out;           // [npts, nch]
  const int npts = in_sizes[0] / 3;           // 32768
  const int nch  = in_sizes[1] / 81;          // 2048

  dim3 grid(nch / BN, npts / BM);             // (16, 256)
  sph_mfma_kernel<<<grid, 256, 0, stream>>>(pos, W, out, nch);
}

// Round 12
// 55.411 us; speedup vs baseline: 1.3758x; 1.3758x over previous
//
#include <hip/hip_runtime.h>

// SphericalEmbedding FINAL (= round 6, best of 11 rounds: 55.45 us, absmax 0.0625).
// bf16 MFMA GEMM, swapped operands (D[ch,pt]), LDS-staged linear epilogue.
//   pre-kernel:  W [81,2048] f32 -> WT [2048][96] bf16 (zero-padded K) in d_ws
//   main kernel: 128 pts x 128 ch per block; harmonics -> bf16 LDS tile;
//                WT rows -> A fragments; D[ch, pt] via mfma_f32_16x16x32_bf16;
//                acc -> LDS C[128][132] -> fully linear f32x4 global stores.
// Probed and refuted at ~5.1 TB/s write plateau: store width (R2/R5/R6 flat),
// nontemporal (-60%), XCD swizzle (-6%), kernel fission (-11%), occupancy
// (flat), in-block W convert (-37%).

typedef __attribute__((ext_vector_type(8))) short bf16x8;
typedef __attribute__((ext_vector_type(4))) float f32x4;

#define BM 128           // points per block
#define BN 128           // channels per block
#define LDA 104          // H row stride (bf16): 208 B -> 2-way aliasing (free)
#define KPAD 96
#define LDSC 132         // C row stride (dwords): +4 pad vs 128

// ---- compile-time normalization table ----------------------------------
constexpr double PI_D = 3.14159265358979323846;
constexpr double csqrt_c(double v) {
  if (v <= 0.0) return 0.0;
  double g = v < 1.0 ? 1.0 : v;
  for (int i = 0; i < 100; ++i) g = 0.5 * (g + v / g);
  return g;
}
struct Norms { float c[81]; };
constexpr Norms make_norms() {
  Norms n{};
  for (int l = 0; l <= 8; ++l)
    for (int m = -l; m <= l; ++m) {
      int am = m < 0 ? -m : m;
      double fr = 1.0;
      for (int i = l - am + 1; i <= l + am; ++i) fr *= (double)i;
      double v = csqrt_c((2.0 * l + 1.0) / (4.0 * PI_D) / fr);
      if (m < 0 && (am & 1)) v = -v;
      n.c[l * l + l + m] = (float)v;
    }
  return n;
}
constexpr Norms NORMS = make_norms();

__device__ __forceinline__ unsigned f2bf(float f) {   // RTN-even f32 -> bf16 bits
  unsigned u = __float_as_uint(f);
  return (u + 0x7fffu + ((u >> 16) & 1u)) >> 16;
}

// ---- pre-kernel: W f32 [81][nch] -> WT bf16 [nch][96] (padded) ---------
__global__ __launch_bounds__(256)
void wt_convert_kernel(const float* __restrict__ W, unsigned short* __restrict__ WT, int nch) {
  const int t = blockIdx.x * 256 + threadIdx.x;    // t in [0, nch*12)
  if (t >= nch * 12) return;
  const int kg = t / nch;                          // k-group of 8 (0..11)
  const int c  = t - kg * nch;                     // lanes -> consecutive c (coalesced)
  unsigned short v[8];
#pragma unroll
  for (int j = 0; j < 8; ++j) {
    const int k = kg * 8 + j;
    v[j] = (k < 81) ? (unsigned short)f2bf(W[(size_t)k * nch + c]) : (unsigned short)0;
  }
  unsigned* dst = reinterpret_cast<unsigned*>(WT + (size_t)c * KPAD + kg * 8);
#pragma unroll
  for (int j = 0; j < 4; ++j)
    dst[j] = (unsigned)v[2 * j] | ((unsigned)v[2 * j + 1] << 16);
}

// ---- main MFMA kernel ---------------------------------------------------
__global__ __launch_bounds__(256)
void sph_mfma_kernel(const float* __restrict__ pos,
                     const unsigned short* __restrict__ WT,
                     float* __restrict__ out, int nch)
{
  // H (bf16 harmonics, 26.6 KB) and C (f32 out-tile, 67.6 KB) time-share LDS.
  __shared__ __align__(16) char smem[BM * LDSC * 4];       // 67584 B
  unsigned short* H = reinterpret_cast<unsigned short*>(smem);
  float*          C = reinterpret_cast<float*>(smem);

  const int tid  = threadIdx.x;
  const int lane = tid & 63;
  const int wid  = tid >> 6;                       // 4 waves: 2(ch) x 2(pt)
  const int wc   = wid >> 1, wp = wid & 1;
  const int l15  = lane & 15, l4 = lane >> 4;
  const int mblk = blockIdx.y, nblk = blockIdx.x;

  // ---- phase 1: harmonics for 128 points -> bf16 rows in LDS -----------
  if (tid < BM) {
    const int gp = mblk * BM + tid;
    const float px = pos[gp * 3 + 0];
    const float py = pos[gp * 3 + 1];
    const float pz = pos[gp * 3 + 2];
    const float r   = sqrtf(px * px + py * py + pz * pz);
    const float inv = 1.0f / (r + 1e-8f);
    const float xn = px * inv, yn = py * inv, zn = pz * inv;
    const float x = fminf(1.0f, fmaxf(-1.0f, zn));     // cos(theta)
    const float s = sqrtf(fmaxf(0.0f, 1.0f - x * x));  // sin(theta)
    const float rho = sqrtf(xn * xn + yn * yn);
    const float c1  = rho > 0.0f ? xn / rho : 1.0f;    // cos(phi)

    float cm[9];
    cm[0] = 1.0f; cm[1] = c1;
#pragma unroll
    for (int m = 2; m <= 8; ++m) cm[m] = 2.0f * c1 * cm[m - 1] - cm[m - 2];

    float P[9][9];
#pragma unroll
    for (int m = 0; m <= 8; ++m) {
      if (m == 0) P[0][0] = 1.0f;
      else        P[m][m] = -(float)(2 * m - 1) * s * P[m - 1][m - 1];
      if (m + 1 <= 8) P[m + 1][m] = (float)(2 * m + 1) * x * P[m][m];
#pragma unroll
      for (int l = m + 2; l <= 8; ++l)
        P[l][m] = ((float)(2 * l - 1) * x * P[l - 1][m]
                   - (float)(l + m - 1) * P[l - 2][m]) / (float)(l - m);
    }

    float y[KPAD];
#pragma unroll
    for (int l = 0; l <= 8; ++l)
#pragma unroll
      for (int m = -l; m <= l; ++m) {
        const int am  = m < 0 ? -m : m;
        const int idx = l * l + l + m;
        y[idx] = NORMS.c[idx] * P[l][am] * cm[am];
      }
#pragma unroll
    for (int i = 81; i < KPAD; ++i) y[i] = 0.0f;

    unsigned* hrow = reinterpret_cast<unsigned*>(&H[tid * LDA]);
#pragma unroll
    for (int i = 0; i < KPAD / 2; ++i)
      hrow[i] = f2bf(y[2 * i]) | (f2bf(y[2 * i + 1]) << 16);
  }

  // ---- A fragments: W channels, direct 16B global loads (L2-resident) --
  bf16x8 wfrag[3][4];
  const unsigned short* wt_base =
      WT + (size_t)(nblk * BN + wc * 64 + l15) * KPAD + l4 * 8;
#pragma unroll
  for (int kk = 0; kk < 3; ++kk)
#pragma unroll
    for (int cmr = 0; cmr < 4; ++cmr)
      wfrag[kk][cmr] = *reinterpret_cast<const bf16x8*>(
          wt_base + (size_t)cmr * 16 * KPAD + kk * 32);

  __syncthreads();

  // ---- MFMA: D[ch, pt], 3 k-steps, 4x4 16x16 tiles per wave -------------
  f32x4 acc[4][4] = {};
#pragma unroll
  for (int kk = 0; kk < 3; ++kk) {
    bf16x8 hfrag[4];
#pragma unroll
    for (int pn = 0; pn < 4; ++pn)
      hfrag[pn] = *reinterpret_cast<const bf16x8*>(
          &H[(wp * 64 + pn * 16 + l15) * LDA + kk * 32 + l4 * 8]);
#pragma unroll
    for (int cmr = 0; cmr < 4; ++cmr)
#pragma unroll
      for (int pn = 0; pn < 4; ++pn)
        acc[cmr][pn] = __builtin_amdgcn_mfma_f32_16x16x32_bf16(
            wfrag[kk][cmr], hfrag[pn], acc[cmr][pn], 0, 0, 0);
  }

  __syncthreads();   // H is now dead; smem becomes the C tile

  // ---- phase 5: acc -> LDS C[pt][ch] -------------------------------------
  // D row (channel) = l4*4 + reg (+16*cmr), D col (point) = l15 (+16*pn)
#pragma unroll
  for (int pn = 0; pn < 4; ++pn) {
    const int crow = wp * 64 + pn * 16 + l15;          // point (local row)
#pragma unroll
    for (int cmr = 0; cmr < 4; ++cmr)
      *reinterpret_cast<f32x4*>(&C[crow * LDSC + wc * 64 + cmr * 16 + l4 * 4]) =
          acc[cmr][pn];
  }

  __syncthreads();

  // ---- phase 7: linear re-emit, 1 KB contiguous per wave instruction -----
  const size_t obase = (size_t)(mblk * BM) * nch + (size_t)nblk * BN;
#pragma unroll
  for (int i = 0; i < 16; ++i) {
    const int f = i * 1024 + tid * 4;                  // flat tile idx (floats)
    const int r = f >> 7;                              // point row 0..127
    const int c = f & 127;                             // channel col
    const f32x4 v = *reinterpret_cast<const f32x4*>(&C[r * LDSC + c]);
    *reinterpret_cast<f32x4*>(out + obase + (size_t)r * nch + c) = v;
  }
}

extern "C" void kernel_launch(void* const* d_in, const int* in_sizes, int n_in,
                              void* d_out, int out_size, void* d_ws, size_t ws_size,
                              hipStream_t stream) {
  const float* pos = (const float*)d_in[0];   // [npts, 3]
  const float* W   = (const float*)d_in[1];   // [81, nch]
  float*       out = (float*)d_out;           // [npts, nch]
  const int npts = in_sizes[0] / 3;           // 32768
  const int nch  = in_sizes[1] / 81;          // 2048

  unsigned short* WT = (unsigned short*)d_ws;  // 384 KB
  wt_convert_kernel<<<(nch * 12 + 255) / 256, 256, 0, stream>>>(W, WT, nch);
  dim3 grid(nch / BN, npts / BM);              // (16, 256)
  sph_mfma_kernel<<<grid, 256, 0, stream>>>(pos, WT, out, nch);
}